// Round 9
// baseline (303.948 us; speedup 1.0000x reference)
//
#include <hip/hip_runtime.h>
#include <hip/hip_bf16.h>

#define B_ 2048
#define L_ 200
#define D_ 256
#define K_ 8

typedef __attribute__((ext_vector_type(8))) _Float16 half8;
typedef __attribute__((ext_vector_type(4))) _Float16 half4v;
typedef __attribute__((ext_vector_type(4))) float f32x4;

#define USTP 28   // UsT row stride f16: 56B rows, 14 dw (8-row group -> 2-way banks)
#define WP   232  // wH/wL row stride
#define CP   264  // cH/cL/Xs row stride

// LDS offsets (bytes); total padded >81920 to pin 1 block/CU (=> 128-reg budget)
#define OFF_UST0 0                       // UsT buf0 [256][28] f16 = 14336
#define OFF_UST1 14336                   // UsT buf1              = 14336
#define OFF_WH   28672                   // wH [16][232] f16      = 7424
#define OFF_WL   36096                   // wL [16][232] f16      = 7424
#define OFF_XA   43520                   // XsA [16][264] f16     = 8448 (overlay cH)
#define OFF_XB   51968                   // XsB [16][264] f16     = 8448 (overlay cL)
#define OFF_LB   60416                   // lb [8][200] f32       = 6400
#define OFF_RED  66816                   // red2 [16][8] f32      = 512
#define LDS_TOTAL 82048                  // padded: pins occupancy to 1 block/CU

// ------------------------------------------------------------------
// Kernel 0: W fp32 -> fp16
// ------------------------------------------------------------------
__global__ __launch_bounds__(256) void w_to_f16(const float* __restrict__ W,
                                                _Float16* __restrict__ Wh) {
    const int idx = (blockIdx.x * 256 + threadIdx.x) * 4;
    const float4 v = *(const float4*)(W + idx);
    half4v h = { (_Float16)v.x, (_Float16)v.y, (_Float16)v.z, (_Float16)v.w };
    *(half4v*)(Wh + idx) = h;
}

// ------------------------------------------------------------------
// Fused kernel: 1024 thr (16 waves) per batch.
// Prologue: u^T = W@X^T (swapped MFMA) -> small UsT dbuf; zf/au frags
// gathered incrementally per tile (bank-clean); 2-deep X prefetch.
// Routing: z-pass + b-update MFMA; w/c hi-lo fp16; scale applied
// post-MFMA (one barrier fewer per iter).
// ------------------------------------------------------------------
__global__ __launch_bounds__(1024, 4) void fused_mie5(
        const float* __restrict__ X, const float* __restrict__ b_init,
        const int* __restrict__ mask, const _Float16* __restrict__ Wh,
        float* __restrict__ out) {
    extern __shared__ char dyn[];
    _Float16* UsT0 = (_Float16*)(dyn + OFF_UST0);
    _Float16* UsT1 = (_Float16*)(dyn + OFF_UST1);
    _Float16* wHs  = (_Float16*)(dyn + OFF_WH);
    _Float16* wLs  = (_Float16*)(dyn + OFF_WL);
    _Float16* XsA  = (_Float16*)(dyn + OFF_XA);
    _Float16* XsB  = (_Float16*)(dyn + OFF_XB);
    _Float16* cHs  = (_Float16*)(dyn + OFF_XA);  // routing overlay
    _Float16* cLs  = (_Float16*)(dyn + OFF_XB);  // routing overlay
    float* lb   = (float*)(dyn + OFF_LB);
    float* red2 = (float*)(dyn + OFF_RED);

    const int b = blockIdx.x;
    const int t = threadIdx.x;
    const int w = t >> 6, lane = t & 63;
    const int fr = lane & 15, hi = lane >> 4;

    // ---------- one-time init ----------
    if (t < 928) *(int4*)(dyn + OFF_WH + 16 * t) = make_int4(0, 0, 0, 0);
    for (int idx = t; idx < K_ * L_; idx += 1024) {
        const int k = idx / L_, l = idx - k * L_;
        lb[idx] = (mask[b * L_ + l] == 0) ? -1e9f
                                          : b_init[(size_t)b * (K_ * L_) + idx];
    }

    // hoisted W frags (MFMA A operand; wave w owns e = 16w..16w+15)
    half8 bw[8];
    {
        const _Float16* wr = Wh + (size_t)(16 * w + fr) * 256;
#pragma unroll
        for (int d0 = 0; d0 < 8; ++d0)
            bw[d0] = *(const half8*)(wr + 32 * d0 + 8 * hi);
    }

    const float* Xb = X + (size_t)b * L_ * D_;
    const int sc4 = lane * 4;

    // stage X tile 0 directly; issue tile-1 load (2-deep pipe primes here)
    {
        const float4 v = *(const float4*)(Xb + w * 256 + sc4);
        half4v h = { (_Float16)v.x, (_Float16)v.y, (_Float16)v.z, (_Float16)v.w };
        *(half4v*)&XsA[w * CP + sc4] = h;
    }
    float4 pf0 = make_float4(0.f, 0.f, 0.f, 0.f);
    float4 pf1 = *(const float4*)(Xb + (16 + w) * 256 + sc4);   // tile 1
    __syncthreads();

    half8 zf[7];
    zf[6] = (half8){ (_Float16)0, (_Float16)0, (_Float16)0, (_Float16)0,
                     (_Float16)0, (_Float16)0, (_Float16)0, (_Float16)0 };
    half8 au[8];

    // ---------- prologue: 13 l-tiles, 2-deep prefetch, 1 barrier/tile ----------
#pragma unroll
    for (int lt = 0; lt < 13; ++lt) {
        _Float16* xcur = (lt & 1) ? XsB : XsA;
        _Float16* xnxt = (lt & 1) ? XsA : XsB;
        _Float16* ucur = (lt & 1) ? UsT1 : UsT0;
        _Float16* uprv = (lt & 1) ? UsT0 : UsT1;

        // 1. issue load for tile lt+2 into pf_{lt&1}
        if (lt <= 10) {
            const int l = 16 * (lt + 2) + w;
            float4 v = make_float4(0.f, 0.f, 0.f, 0.f);
            if (lt < 10) {
                v = *(const float4*)(Xb + l * 256 + sc4);
            } else {
                if (l < L_) v = *(const float4*)(Xb + l * 256 + sc4);
            }
            if (lt & 1) pf1 = v; else pf0 = v;
        }

        // 2. u^T tile MFMA: D[e][l] = sum_d W[e,d] X[l,d]
        f32x4 acc = {};
#pragma unroll
        for (int d0 = 0; d0 < 8; ++d0) {
            const half8 a8 = *(const half8*)&xcur[fr * CP + 32 * d0 + 8 * hi];
            acc = __builtin_amdgcn_mfma_f32_16x16x32_f16(bw[d0], a8, acc, 0, 0, 0);
        }

        // 3. gather tile lt-1 register frags from the previous UsT buffer
        if (lt > 0) {
            const int pt = lt - 1;
            if ((hi >> 1) == (pt & 1)) {
                const int base = (16 * w + fr) * USTP + 8 * (hi & 1);
                const half4v p0 = *(const half4v*)&uprv[base];
                const half4v p1 = *(const half4v*)&uprv[base + 4];
                half8 v;
                v[0] = p0[0]; v[1] = p0[1]; v[2] = p0[2]; v[3] = p0[3];
                v[4] = p1[0]; v[5] = p1[1]; v[6] = p1[2]; v[7] = p1[3];
                zf[pt >> 1] = v;
            }
            if (w == pt) {
#pragma unroll
                for (int d0 = 0; d0 < 8; ++d0) {
                    _Float16 tmp[8];
#pragma unroll
                    for (int j = 0; j < 8; ++j)
                        tmp[j] = uprv[(32 * d0 + 8 * hi + j) * USTP + fr];
                    au[d0] = *(half8*)tmp;
                }
            }
        }

        // 4. write u^T C-frags: row e=16w+4hi+j, col r=fr (conflict-free)
#pragma unroll
        for (int j = 0; j < 4; ++j)
            ucur[(16 * w + 4 * hi + j) * USTP + fr] = (_Float16)acc[j];

        // 5. stage prefetched tile lt+1
        if (lt < 12) {
            const float4 v = ((lt + 1) & 1) ? pf1 : pf0;
            half4v h = { (_Float16)v.x, (_Float16)v.y, (_Float16)v.z, (_Float16)v.w };
            *(half4v*)&xnxt[w * CP + sc4] = h;
        }
        __syncthreads();
    }
    // final gather: tile 12 (even -> UsT0)
    {
        if ((hi >> 1) == 0) {
            const int base = (16 * w + fr) * USTP + 8 * (hi & 1);
            const half4v p0 = *(const half4v*)&UsT0[base];
            const half4v p1 = *(const half4v*)&UsT0[base + 4];
            half8 v;
            v[0] = p0[0]; v[1] = p0[1]; v[2] = p0[2]; v[3] = p0[3];
            v[4] = p1[0]; v[5] = p1[1]; v[6] = p1[2]; v[7] = p1[3];
            zf[6] = v;
        }
        if (w == 12) {
#pragma unroll
            for (int d0 = 0; d0 < 8; ++d0) {
                _Float16 tmp[8];
#pragma unroll
                for (int j = 0; j < 8; ++j)
                    tmp[j] = UsT0[(32 * d0 + 8 * hi + j) * USTP + fr];
                au[d0] = *(half8*)tmp;
            }
        }
    }

    // ---------- routing iterations ----------
    for (int iter = 0; iter < 3; ++iter) {
        // A. softmax over l (waves 0..7, wave = capsule k); hi/lo fp16 w
        if (t < 512) {
            const int k = t >> 6, ln = t & 63;
            float v[4];
            float m = -1e30f;
#pragma unroll
            for (int i = 0; i < 4; ++i) {
                const int l = ln + 64 * i;
                v[i] = (l < L_) ? lb[k * L_ + l] : -1e30f;
                m = fmaxf(m, v[i]);
            }
#pragma unroll
            for (int off = 32; off >= 1; off >>= 1)
                m = fmaxf(m, __shfl_xor(m, off));
            float e[4], s = 0.f;
#pragma unroll
            for (int i = 0; i < 4; ++i) {
                const int l = ln + 64 * i;
                e[i] = (l < L_) ? __expf(v[i] - m) : 0.f;
                s += e[i];
            }
#pragma unroll
            for (int off = 32; off >= 1; off >>= 1)
                s += __shfl_xor(s, off);
            const float rinv = 1.0f / s;
#pragma unroll
            for (int i = 0; i < 4; ++i) {
                const int l = ln + 64 * i;
                if (l < L_) {
                    const float wv = e[i] * rinv;
                    const _Float16 h = (_Float16)wv;
                    wHs[k * WP + l] = h;
                    wLs[k * WP + l] = (_Float16)(wv - (float)h);
                }
            }
        }
        __syncthreads();                                     // B1

        // B. z-pass MFMA: A = wH/wL (LDS), B = zf (regs)
        f32x4 zH = {}, zL = {};
#pragma unroll
        for (int ks = 0; ks < 7; ++ks) {
            const half8 ah = *(const half8*)&wHs[fr * WP + 32 * ks + 8 * hi];
            const half8 al = *(const half8*)&wLs[fr * WP + 32 * ks + 8 * hi];
            zH = __builtin_amdgcn_mfma_f32_16x16x32_f16(ah, zf[ks], zH, 0, 0, 0);
            zL = __builtin_amdgcn_mfma_f32_16x16x32_f16(al, zf[ks], zL, 0, 0, 0);
        }
        const float z0 = zH[0] + zL[0], z1 = zH[1] + zL[1];
        const float z2 = zH[2] + zL[2], z3 = zH[3] + zL[3];

        // C. store UNSCALED z as hi/lo c (scale applied post-MFMA later)
        if (iter < 2 && hi < 2) {
            const _Float16 h0 = (_Float16)z0, h1 = (_Float16)z1;
            const _Float16 h2 = (_Float16)z2, h3 = (_Float16)z3;
            const int cb = 16 * w + fr;
            cHs[(4 * hi + 0) * CP + cb] = h0;
            cHs[(4 * hi + 1) * CP + cb] = h1;
            cHs[(4 * hi + 2) * CP + cb] = h2;
            cHs[(4 * hi + 3) * CP + cb] = h3;
            cLs[(4 * hi + 0) * CP + cb] = (_Float16)(z0 - (float)h0);
            cLs[(4 * hi + 1) * CP + cb] = (_Float16)(z1 - (float)h1);
            cLs[(4 * hi + 2) * CP + cb] = (_Float16)(z2 - (float)h2);
            cLs[(4 * hi + 3) * CP + cb] = (_Float16)(z3 - (float)h3);
        }
        // norms partials
        float sq0 = z0 * z0, sq1 = z1 * z1, sq2 = z2 * z2, sq3 = z3 * z3;
#pragma unroll
        for (int off = 1; off <= 8; off <<= 1) {
            sq0 += __shfl_xor(sq0, off);
            sq1 += __shfl_xor(sq1, off);
            sq2 += __shfl_xor(sq2, off);
            sq3 += __shfl_xor(sq3, off);
        }
        if (fr == 0 && hi < 2) {
            f32x4 sv = { sq0, sq1, sq2, sq3 };
            *(f32x4*)&red2[w * 8 + 4 * hi] = sv;
        }
        __syncthreads();                                     // B2

        // D. squash scale, redundant per wave
        float myscale = 0.f;
        if (lane < 8) {
            float ns = 0.f;
#pragma unroll
            for (int ww = 0; ww < 16; ++ww) ns += red2[ww * 8 + lane];
            myscale = ns / ((1.f + ns) * sqrtf(ns + 1e-8f));
        }

        if (iter == 2) {
            const float sc0 = __shfl(myscale, 4 * hi + 0);
            const float sc1 = __shfl(myscale, 4 * hi + 1);
            const float sc2 = __shfl(myscale, 4 * hi + 2);
            const float sc3 = __shfl(myscale, 4 * hi + 3);
            if (hi < 2) {
                float* op = out + (size_t)b * (K_ * D_) + (4 * hi) * D_ + 16 * w + fr;
                op[0 * D_] = sc0 * z0;
                op[1 * D_] = sc1 * z1;
                op[2 * D_] = sc2 * z2;
                op[3 * D_] = sc3 * z3;
            }
        } else {
            // E. b-update MFMA on unscaled c; scale applied to the output
            if (w < 13) {
                f32x4 dH = {}, dL = {};
#pragma unroll
                for (int d0 = 0; d0 < 8; ++d0) {
                    const half8 bh = *(const half8*)&cHs[fr * CP + 32 * d0 + 8 * hi];
                    const half8 bl = *(const half8*)&cLs[fr * CP + 32 * d0 + 8 * hi];
                    dH = __builtin_amdgcn_mfma_f32_16x16x32_f16(au[d0], bh, dH, 0, 0, 0);
                    dL = __builtin_amdgcn_mfma_f32_16x16x32_f16(au[d0], bl, dL, 0, 0, 0);
                }
                const float scf = __shfl(myscale, fr & 7);   // scale[k=fr]
                if (fr < 8) {
#pragma unroll
                    for (int j = 0; j < 4; ++j) {
                        const int l = 16 * w + 4 * hi + j;
                        if (l < L_) lb[fr * L_ + l] += (dH[j] + dL[j]) * scf;
                    }
                }
            }
            __syncthreads();                                 // B3
        }
    }
}

// ==================================================================
extern "C" void kernel_launch(void* const* d_in, const int* in_sizes, int n_in,
                              void* d_out, int out_size, void* d_ws, size_t ws_size,
                              hipStream_t stream) {
    (void)in_sizes; (void)n_in; (void)out_size; (void)ws_size;
    const float* behavior = (const float*)d_in[0];   // [B, L, D]
    const float* W        = (const float*)d_in[1];   // [D, D]
    const float* b_init   = (const float*)d_in[2];   // [B, K, L]
    const int*   mask     = (const int*)d_in[3];     // [B, L]
    float* out      = (float*)d_out;                 // [B, K, D]
    _Float16* Wh    = (_Float16*)d_ws;               // [256,256] fp16

    hipFuncSetAttribute((const void*)fused_mie5,
                        hipFuncAttributeMaxDynamicSharedMemorySize, LDS_TOTAL);

    w_to_f16<<<64, 256, 0, stream>>>(W, Wh);
    fused_mie5<<<B_, 1024, LDS_TOTAL, stream>>>(behavior, b_init, mask, Wh, out);
}